// Round 18
// baseline (305.844 us; speedup 1.0000x reference)
//
#include <hip/hip_runtime.h>
#include <hip/hip_cooperative_groups.h>
#include <hip/hip_bf16.h>
#include <math.h>

namespace cg = cooperative_groups;

typedef float4 f4;
typedef __attribute__((ext_vector_type(8))) short bf16x8;
typedef __attribute__((ext_vector_type(4))) float f32x4;
typedef __attribute__((ext_vector_type(16))) float f32x16;

#define CD   768
#define SEQ  1024
#define NHD  12
#define DH   64

__device__ __forceinline__ ushort f2bf(float x) {
    union { __hip_bfloat16 h; ushort u; } v;
    v.h = __float2bfloat16(x);
    return v.u;
}
__device__ __forceinline__ unsigned pk2bf(float a, float b) {
    union { __hip_bfloat162 h; unsigned u; } v;
    v.h = __float22bfloat162_rn(make_float2(a, b));
    return v.u;
}
__device__ __forceinline__ bf16x8 mk_bf16x8(unsigned a, unsigned b, unsigned c, unsigned d) {
    union { unsigned u[4]; bf16x8 v; } r;
    r.u[0] = a; r.u[1] = b; r.u[2] = c; r.u[3] = d;
    return r.v;
}
__device__ __forceinline__ void gload_lds16(const ushort* g, ushort* l) {
    __builtin_amdgcn_global_load_lds((const __attribute__((address_space(1))) void*)g,
                                     (__attribute__((address_space(3))) void*)l, 16, 0, 0);
}

// =================== phase bodies (shared by mega + fallback) ===================

__device__ __forceinline__ void dev_cvt(
    int idx, const float* __restrict__ x, const float* __restrict__ Wq,
    const float* __restrict__ Wk, const float* __restrict__ Wv,
    const float* __restrict__ pw, ushort* __restrict__ ws)
{
    const int e = idx << 2;
    if (e < 4915200) {
        const float* src; int off;
        if      (e < 3145728) { src = x;  off = e; }
        else if (e < 3735552) { src = Wq; off = e - 3145728; }
        else if (e < 4325376) { src = Wk; off = e - 3735552; }
        else                  { src = Wv; off = e - 4325376; }
        const f4 v = *(const f4*)(src + off);
        uint2 o;
        o.x = pk2bf(v.x, v.y);
        o.y = pk2bf(v.z, v.w);
        *(uint2*)(ws + e) = o;
    } else {
        const int off = e - 4915200;          // pw linear = n*768 + k
        const int n = off / CD, k = off - n * CD;
        const f4 v = *(const f4*)(pw + off);
        uint2 o;
        o.x = pk2bf(v.x, v.y);
        o.y = pk2bf(v.z, v.w);
        *(uint2*)(ws + 4915200 + ((size_t)(k >> 6) * CD + n) * 64 + (k & 63)) = o;
    }
}

// QKV 128x96 tile, single-buffered LDS (14,336 ushorts = 28,672 B)
__device__ __forceinline__ void dev_qkv(
    int tile, ushort* Sq,
    const ushort* __restrict__ xbf,
    const ushort* __restrict__ wqbf, const ushort* __restrict__ wkbf, const ushort* __restrict__ wvbf,
    const float* __restrict__ bq, const float* __restrict__ bk, const float* __restrict__ bv,
    ushort* __restrict__ qbf, ushort* __restrict__ kbf, ushort* __restrict__ vbfT)
{
    const int t = threadIdx.x;
    const int w = t >> 6, l = t & 63;
    const int lr = l & 15, lg = l >> 4;
    const int n0 = (tile % 24) * 96;
    const int m0 = (tile / 24) << 7;
    const int sel  = n0 / CD;
    const int nloc = n0 % CD;
    const ushort* Wb  = (sel == 0) ? wqbf : ((sel == 1) ? wkbf : wvbf);
    const float* bias = (sel == 0) ? bq : ((sel == 1) ? bk : bv);

    const int srow = (w << 3) + (l >> 3);
    const int scol = (l & 7) << 3;
    const ushort* Agl = xbf + (size_t)(m0 + srow) * CD + scol;
    const ushort* Bgl = Wb + (size_t)(nloc + srow) * CD + scol;

    f32x4 acc[4][3];
    #pragma unroll
    for (int mi = 0; mi < 4; ++mi)
        #pragma unroll
        for (int ni = 0; ni < 3; ++ni) acc[mi][ni] = (f32x4){0.f, 0.f, 0.f, 0.f};

    const int mb = (w >> 1) << 6;
    const int nb = (w & 1) * 48;

    for (int kt = 0; kt < 12; ++kt) {
        const int kc = kt << 6;
        __syncthreads();                 // prev compute done reading Sq
        #pragma unroll
        for (int i = 0; i < 4; ++i)
            gload_lds16(Agl + (size_t)(i << 5) * CD + kc, &Sq[(i << 11) + (w << 9)]);
        #pragma unroll
        for (int i = 0; i < 3; ++i)
            gload_lds16(Bgl + (size_t)(i << 5) * CD + kc, &Sq[8192 + (i << 11) + (w << 9)]);
        __syncthreads();                 // staging complete
        #pragma unroll
        for (int kk = 0; kk < 2; ++kk) {
            bf16x8 af[4], bf[3];
            #pragma unroll
            for (int mi = 0; mi < 4; ++mi)
                af[mi] = *(const bf16x8*)&Sq[(mb + (mi << 4) + lr) * 64 + (kk << 5) + (lg << 3)];
            #pragma unroll
            for (int ni = 0; ni < 3; ++ni)
                bf[ni] = *(const bf16x8*)&Sq[8192 + (nb + (ni << 4) + lr) * 64 + (kk << 5) + (lg << 3)];
            #pragma unroll
            for (int mi = 0; mi < 4; ++mi)
                #pragma unroll
                for (int ni = 0; ni < 3; ++ni)
                    acc[mi][ni] = __builtin_amdgcn_mfma_f32_16x16x32_bf16(af[mi], bf[ni], acc[mi][ni], 0, 0, 0);
        }
    }
    __syncthreads();                     // Sq reusable

    ushort* Ep = Sq + w * 3072;          // per-wave 64x48 (q/k) or 48x64 (v)

    float bl[3];
    #pragma unroll
    for (int ni = 0; ni < 3; ++ni) bl[ni] = bias[nloc + nb + (ni << 4) + lr];

    if (sel < 2) {
        #pragma unroll
        for (int mi = 0; mi < 4; ++mi)
            #pragma unroll
            for (int ni = 0; ni < 3; ++ni)
                #pragma unroll
                for (int reg = 0; reg < 4; ++reg)
                    Ep[((mi << 4) + (lg << 2) + reg) * 48 + (ni << 4) + lr] =
                        f2bf(acc[mi][ni][reg] + bl[ni]);
    } else {
        // V: transpose + pi-permute: key = mi*16+lg*4+reg ->
        // slot = (mi>>1)*32 + lg*8 + (mi&1)*4 + reg
        #pragma unroll
        for (int mi = 0; mi < 4; ++mi)
            #pragma unroll
            for (int ni = 0; ni < 3; ++ni)
                #pragma unroll
                for (int reg = 0; reg < 4; ++reg)
                    Ep[((ni << 4) + lr) * 64 +
                       ((mi >> 1) << 5) + (lg << 3) + ((mi & 1) << 2) + reg] =
                        f2bf(acc[mi][ni][reg] + bl[ni]);
    }
    __syncthreads();

    const int bi  = m0 >> 10;
    const int si0 = (m0 & 1023) + mb;
    if (sel < 2) {
        ushort* dbf = (sel == 0) ? qbf : kbf;
        #pragma unroll
        for (int i = 0; i < 6; ++i) {
            const int c0   = i << 3;
            const int head = (nloc + nb + c0) >> 6;
            const int dd0  = (nloc + nb + c0) & 63;
            const int bn   = bi * NHD + head;
            *(bf16x8*)(dbf + (((size_t)bn << 10) + si0 + l) * 64 + dd0) =
                *(const bf16x8*)(Ep + l * 48 + c0);
        }
    } else {
        #pragma unroll
        for (int i = 0; i < 6; ++i) {
            const int idx = (i << 6) + l;
            const int r   = idx >> 3, ch = idx & 7;
            const int head = (nloc + nb + r) >> 6;
            const int d    = (nloc + nb + r) & 63;
            const int bn   = bi * NHD + head;
            *(bf16x8*)(vbfT + (((size_t)(bn * DH + d)) << 10) + si0 + (ch << 3)) =
                *(const bf16x8*)(Ep + r * 64 + (ch << 3));
        }
    }
}

// attention + fused rel prologue; SMEM must be >= 20,480 ushorts (40,960 B)
__device__ __forceinline__ void dev_attn(
    int tile, ushort* SMEM,
    const ushort* __restrict__ qbf, const ushort* __restrict__ kbf,
    const ushort* __restrict__ vbfT,
    const float* __restrict__ rph, const float* __restrict__ rpw,
    ushort* __restrict__ abf2)
{
    ushort (*KV)[8192] = (ushort(*)[8192])SMEM;
    float* rhs_ = (float*)(SMEM + 16384);

    const int t  = threadIdx.x;
    const int l  = t & 63, w = t >> 6;
    const int lr = l & 15, lg = l >> 4;
    const int qt = tile & 15, bn = tile >> 4;
    const int q0 = qt << 6;

    __syncthreads();

    // -------- rel prologue (R12-verified math) --------
    {
        const int p   = w >> 1;
        const int sub = w & 1;
        const int h   = (qt << 1) + p;
        const int q5  = l & 31, g = l >> 5;

        const ushort* qp = qbf + (((size_t)bn << 10) + (h << 5) + q5) * 64 + (g << 3);
        bf16x8 qf[4];
        #pragma unroll
        for (int c = 0; c < 4; ++c) qf[c] = *(const bf16x8*)(qp + (c << 4));

        float* PwF = (float*)&KV[0][0] + p * 2112;   // [64][33] scratch

        if (sub == 0) {
            f32x16 acch;
            #pragma unroll
            for (int i = 0; i < 16; ++i) acch[i] = 0.f;
            {
                const float* rp = rph + (size_t)(h + 31 - q5) * 64 + (g << 3);
                #pragma unroll
                for (int c = 0; c < 4; ++c) {
                    const f4 v0 = *(const f4*)(rp + (c << 4));
                    const f4 v1 = *(const f4*)(rp + (c << 4) + 4);
                    union { unsigned u[4]; bf16x8 v; } u;
                    u.u[0] = pk2bf(v0.x, v0.y); u.u[1] = pk2bf(v0.z, v0.w);
                    u.u[2] = pk2bf(v1.x, v1.y); u.u[3] = pk2bf(v1.z, v1.w);
                    acch = __builtin_amdgcn_mfma_f32_32x32x16_bf16(u.v, qf[c], acch, 0, 0, 0);
                }
            }
            #pragma unroll
            for (int r = 0; r < 16; r += 2) {
                const int k2 = (r & 3) + ((r >> 2) << 3) + (g << 2);
                *(float2*)&rhs_[((k2 >> 1) << 7) + (((p << 5) + q5) << 1)] =
                    make_float2(acch[r], acch[r + 1]);
            }
            f32x16 accw;
            #pragma unroll
            for (int i = 0; i < 16; ++i) accw[i] = 0.f;
            {
                const float* rp = rpw + (size_t)q5 * 64 + (g << 3);
                #pragma unroll
                for (int c = 0; c < 4; ++c) {
                    const f4 v0 = *(const f4*)(rp + (c << 4));
                    const f4 v1 = *(const f4*)(rp + (c << 4) + 4);
                    union { unsigned u[4]; bf16x8 v; } u;
                    u.u[0] = pk2bf(v0.x, v0.y); u.u[1] = pk2bf(v0.z, v0.w);
                    u.u[2] = pk2bf(v1.x, v1.y); u.u[3] = pk2bf(v1.z, v1.w);
                    accw = __builtin_amdgcn_mfma_f32_32x32x16_bf16(u.v, qf[c], accw, 0, 0, 0);
                }
            }
            #pragma unroll
            for (int r = 0; r < 16; ++r) {
                const int row = (r & 3) + ((r >> 2) << 3) + (g << 2);
                PwF[row * 33 + q5] = accw[r];
            }
        } else {
            f32x16 accw;
            #pragma unroll
            for (int i = 0; i < 16; ++i) accw[i] = 0.f;
            {
                const bool ok = (32 + q5) < 63;
                const float* rp = rpw + (size_t)(32 + q5) * 64 + (g << 3);
                #pragma unroll
                for (int c = 0; c < 4; ++c) {
                    union { unsigned u[4]; bf16x8 v; } u;
                    if (ok) {
                        const f4 v0 = *(const f4*)(rp + (c << 4));
                        const f4 v1 = *(const f4*)(rp + (c << 4) + 4);
                        u.u[0] = pk2bf(v0.x, v0.y); u.u[1] = pk2bf(v0.z, v0.w);
                        u.u[2] = pk2bf(v1.x, v1.y); u.u[3] = pk2bf(v1.z, v1.w);
                    } else {
                        u.u[0] = 0u; u.u[1] = 0u; u.u[2] = 0u; u.u[3] = 0u;
                    }
                    accw = __builtin_amdgcn_mfma_f32_32x32x16_bf16(u.v, qf[c], accw, 0, 0, 0);
                }
            }
            #pragma unroll
            for (int r = 0; r < 16; ++r) {
                const int row = (r & 3) + ((r >> 2) << 3) + (g << 2) + 32;
                PwF[row * 33 + q5] = accw[r];
            }
        }
    }
    __syncthreads();

    float rw8[8];
    {
        const int p   = w >> 1;
        const int q5w = ((w & 1) << 4) + lr;
        const float* PwF = (float*)&KV[0][0] + p * 2112;
        #pragma unroll
        for (int b = 0; b < 2; ++b)
            #pragma unroll
            for (int reg = 0; reg < 4; ++reg) {
                const int k2 = (b << 4) + (lg << 2) + reg;
                rw8[(b << 2) + reg] = PwF[(q5w + 31 - k2) * 33 + q5w];
            }
    }
    __syncthreads();   // Pw scratch dead; KV staging may begin

    // -------- main loop (R15-verified: swapped QK^T, in-register P) ----
    const ushort* qp = qbf + (((size_t)bn << 10) + q0 + w * 16 + lr) * DH + lg * 8;
    const bf16x8 qa0 = *(const bf16x8*)qp;
    const bf16x8 qa1 = *(const bf16x8*)(qp + 32);

    const int rhbase = (w * 16 + lr) << 1;

    const int i0   = w << 1;
    const int rsub = l >> 3;
    const int coff = ((l & 7) ^ rsub) << 3;
    const size_t kbase = ((size_t)bn << 16);
    const ushort* kp0 = kbf + kbase + (size_t)((i0 << 3) + rsub) * 64 + coff;
    const ushort* kp1 = kp0 + 512;
    const ushort* vp0 = vbfT + kbase + ((size_t)((i0 << 3) + rsub) << 10) + coff;
    const ushort* vp1 = vp0 + 8192;
    const int lds0 = i0 << 9;

    f32x4 oc[4];
    #pragma unroll
    for (int nf = 0; nf < 4; ++nf) oc[nf] = (f32x4){0.f, 0.f, 0.f, 0.f};
    f32x4 sumc = (f32x4){0.f, 0.f, 0.f, 0.f};
    bf16x8 ones;
    #pragma unroll
    for (int i = 0; i < 8; ++i) ones[i] = (short)0x3F80;

    const int s0c = lg ^ (lr & 7);

    gload_lds16(kp0, &KV[0][lds0]);
    gload_lds16(kp1, &KV[0][lds0 + 512]);
    gload_lds16(vp0, &KV[0][4096 + lds0]);
    gload_lds16(vp1, &KV[0][4096 + lds0 + 512]);
    __syncthreads();

    for (int kt = 0; kt < 16; ++kt) {
        const int cur = kt & 1;
        if (kt < 15) {
            ushort* nb_ = &KV[cur ^ 1][0];
            gload_lds16(kp0 + ((kt + 1) << 12), nb_ + lds0);
            gload_lds16(kp1 + ((kt + 1) << 12), nb_ + lds0 + 512);
            gload_lds16(vp0 + ((kt + 1) << 6), nb_ + 4096 + lds0);
            gload_lds16(vp1 + ((kt + 1) << 6), nb_ + 4096 + lds0 + 512);
        }
        const ushort* Kl = &KV[cur][0];
        const ushort* Vt = &KV[cur][4096];
        const float2 rh = *(const float2*)&rhs_[(kt << 7) + rhbase];

        f32x4 sc[4];
        #pragma unroll
        for (int f = 0; f < 4; ++f) {
            f32x4 c = (f32x4){0.f, 0.f, 0.f, 0.f};
            const int rb = (f * 16 + lr) * 64;
            const bf16x8 kb0 = *(const bf16x8*)&Kl[rb + (s0c << 3)];
            const bf16x8 kb1 = *(const bf16x8*)&Kl[rb + ((s0c ^ 4) << 3)];
            c = __builtin_amdgcn_mfma_f32_16x16x32_bf16(kb0, qa0, c, 0, 0, 0);
            c = __builtin_amdgcn_mfma_f32_16x16x32_bf16(kb1, qa1, c, 0, 0, 0);
            sc[f] = c;
        }

        unsigned ua[4], ub[4];
        #pragma unroll
        for (int f = 0; f < 4; ++f) {
            const float rhv = (f & 2) ? rh.y : rh.x;
            const int rb8 = (f & 1) << 2;
            const float e0 = __expf(fmaf(sc[f][0], 0.125f, rhv + rw8[rb8 + 0]));
            const float e1 = __expf(fmaf(sc[f][1], 0.125f, rhv + rw8[rb8 + 1]));
            const float e2 = __expf(fmaf(sc[f][2], 0.125f, rhv + rw8[rb8 + 2]));
            const float e3 = __expf(fmaf(sc[f][3], 0.125f, rhv + rw8[rb8 + 3]));
            unsigned* du = (f & 2) ? ub : ua;
            du[((f & 1) << 1) + 0] = pk2bf(e0, e1);
            du[((f & 1) << 1) + 1] = pk2bf(e2, e3);
        }
        const bf16x8 pa0 = mk_bf16x8(ua[0], ua[1], ua[2], ua[3]);
        const bf16x8 pa1 = mk_bf16x8(ub[0], ub[1], ub[2], ub[3]);

        sumc = __builtin_amdgcn_mfma_f32_16x16x32_bf16(pa0, ones, sumc, 0, 0, 0);
        sumc = __builtin_amdgcn_mfma_f32_16x16x32_bf16(pa1, ones, sumc, 0, 0, 0);
        #pragma unroll
        for (int nf = 0; nf < 4; ++nf) {
            const int rb = (nf * 16 + lr) * 64;
            const bf16x8 vb0 = *(const bf16x8*)&Vt[rb + (s0c << 3)];
            const bf16x8 vb1 = *(const bf16x8*)&Vt[rb + ((s0c ^ 4) << 3)];
            oc[nf] = __builtin_amdgcn_mfma_f32_16x16x32_bf16(pa0, vb0, oc[nf], 0, 0, 0);
            oc[nf] = __builtin_amdgcn_mfma_f32_16x16x32_bf16(pa1, vb1, oc[nf], 0, 0, 0);
        }
        __syncthreads();
    }

    const int bi = bn / NHD, hn = bn - bi * NHD;
    #pragma unroll
    for (int reg = 0; reg < 4; ++reg) {
        const float inv = 1.f / sumc[reg];
        const int row = q0 + w * 16 + lg * 4 + reg;
        ushort* dst = abf2 + ((size_t)hn * 4096 + (bi << 10) + row) * 64 + lr;
        union { unsigned u; ushort2 s2; } a, b;
        a.u = pk2bf(oc[0][reg] * inv, oc[1][reg] * inv);
        b.u = pk2bf(oc[2][reg] * inv, oc[3][reg] * inv);
        dst[0]  = a.s2.x;
        dst[16] = a.s2.y;
        dst[32] = b.s2.x;
        dst[48] = b.s2.y;
    }
}

// proj 64x96 tile, dbuf (20,480 ushorts = 40,960 B)
__device__ __forceinline__ void dev_proj(
    int tile, ushort* Sp,
    const ushort* __restrict__ abf2, const ushort* __restrict__ pwbf,
    const float* __restrict__ pb, float* __restrict__ out)
{
    const int t = threadIdx.x;
    const int w = t >> 6, l = t & 63;
    const int lr = l & 15, lg = l >> 4;
    const int n0 = (tile & 7) * 96;
    const int m0 = (tile >> 3) << 6;

    const int srow = l >> 3;
    const int scol = (l & 7) << 3;
    const ushort* Agl = abf2 + (size_t)(m0 + (w << 4) + srow) * 64 + scol;
    const ushort* Bgl = pwbf + (size_t)(n0 + w * 24 + srow) * 64 + scol;

    f32x4 acc[2][3];
    #pragma unroll
    for (int mi = 0; mi < 2; ++mi)
        #pragma unroll
        for (int ni = 0; ni < 3; ++ni) acc[mi][ni] = (f32x4){0.f, 0.f, 0.f, 0.f};

    const int mb = (w >> 1) << 5;
    const int nb = (w & 1) * 48;

    __syncthreads();
    #pragma unroll
    for (int i = 0; i < 2; ++i)
        gload_lds16(Agl + (i << 9), &Sp[(w << 10) + (i << 9)]);
    #pragma unroll
    for (int j = 0; j < 3; ++j)
        gload_lds16(Bgl + (j << 9), &Sp[4096 + w * 1536 + (j << 9)]);
    __syncthreads();

    for (int kt = 0; kt < 12; ++kt) {
        const int cb = (kt & 1) * 10240;
        if (kt < 11) {
            const int nbuf = ((kt + 1) & 1) * 10240;
            const size_t pA = (size_t)(kt + 1) * 262144;
            const size_t pB = (size_t)(kt + 1) * 49152;
            #pragma unroll
            for (int i = 0; i < 2; ++i)
                gload_lds16(Agl + pA + (i << 9), &Sp[nbuf + (w << 10) + (i << 9)]);
            #pragma unroll
            for (int j = 0; j < 3; ++j)
                gload_lds16(Bgl + pB + (j << 9), &Sp[nbuf + 4096 + w * 1536 + (j << 9)]);
        }
        #pragma unroll
        for (int kk = 0; kk < 2; ++kk) {
            bf16x8 af[2], bf[3];
            #pragma unroll
            for (int mi = 0; mi < 2; ++mi)
                af[mi] = *(const bf16x8*)&Sp[cb + (mb + (mi << 4) + lr) * 64 + (kk << 5) + (lg << 3)];
            #pragma unroll
            for (int ni = 0; ni < 3; ++ni)
                bf[ni] = *(const bf16x8*)&Sp[cb + 4096 + (nb + (ni << 4) + lr) * 64 + (kk << 5) + (lg << 3)];
            #pragma unroll
            for (int mi = 0; mi < 2; ++mi)
                #pragma unroll
                for (int ni = 0; ni < 3; ++ni)
                    acc[mi][ni] = __builtin_amdgcn_mfma_f32_16x16x32_bf16(af[mi], bf[ni], acc[mi][ni], 0, 0, 0);
        }
        __syncthreads();
    }

    float bl[3];
    #pragma unroll
    for (int ni = 0; ni < 3; ++ni) bl[ni] = pb[n0 + nb + (ni << 4) + lr];
    #pragma unroll
    for (int mi = 0; mi < 2; ++mi)
        #pragma unroll
        for (int ni = 0; ni < 3; ++ni)
            #pragma unroll
            for (int reg = 0; reg < 4; ++reg)
                out[(size_t)(m0 + mb + (mi << 4) + (lg << 2) + reg) * CD
                    + n0 + nb + (ni << 4) + lr] = acc[mi][ni][reg] + bl[ni];
}

// =================== cooperative mega-kernel (grid-size agnostic) ==============
__global__ __launch_bounds__(256, 3) void mega_k(
    const float* __restrict__ x,
    const float* __restrict__ Wq, const float* __restrict__ Wk, const float* __restrict__ Wv,
    const float* __restrict__ bq, const float* __restrict__ bk, const float* __restrict__ bv,
    const float* __restrict__ rph, const float* __restrict__ rpw,
    const float* __restrict__ pw, const float* __restrict__ pb,
    float* __restrict__ out, ushort* __restrict__ ws)
{
    __shared__ __align__(16) ushort SMEM[20480];   // 40,960 B

    ushort* xbf  = ws;
    ushort* wqbf = ws + 3145728;
    ushort* wkbf = wqbf + 589824;
    ushort* wvbf = wkbf + 589824;
    ushort* pwbf = wvbf + 589824;
    ushort* qbf  = pwbf + 589824;
    ushort* kbf  = qbf  + 3145728;
    ushort* vbfT = kbf  + 3145728;
    ushort* abf2 = vbfT + 3145728;

    cg::grid_group grid = cg::this_grid();

    for (int idx = blockIdx.x * 256 + threadIdx.x; idx < 1376256; idx += gridDim.x << 8)
        dev_cvt(idx, x, Wq, Wk, Wv, pw, ws);
    __threadfence();
    grid.sync();

    for (int tile = blockIdx.x; tile < 768; tile += gridDim.x)
        dev_qkv(tile, SMEM, xbf, wqbf, wkbf, wvbf, bq, bk, bv, qbf, kbf, vbfT);
    __threadfence();
    grid.sync();

    for (int tile = blockIdx.x; tile < 768; tile += gridDim.x)
        dev_attn(tile, SMEM, qbf, kbf, vbfT, rph, rpw, abf2);
    __threadfence();
    grid.sync();

    for (int tile = blockIdx.x; tile < 512; tile += gridDim.x)
        dev_proj(tile, SMEM, abf2, pwbf, pb, out);
}

// =================== fallback standalone kernels ===============================
__global__ __launch_bounds__(256, 2) void cvt_k(
    const float* __restrict__ x, const float* __restrict__ Wq,
    const float* __restrict__ Wk, const float* __restrict__ Wv,
    const float* __restrict__ pw, ushort* __restrict__ ws)
{
    const int idx = blockIdx.x * 256 + threadIdx.x;
    if (idx < 1376256) dev_cvt(idx, x, Wq, Wk, Wv, pw, ws);
}

__global__ __launch_bounds__(256, 2) void qkv_k(
    const ushort* __restrict__ xbf,
    const ushort* __restrict__ wqbf, const ushort* __restrict__ wkbf, const ushort* __restrict__ wvbf,
    const float* __restrict__ bq, const float* __restrict__ bk, const float* __restrict__ bv,
    ushort* __restrict__ qbf, ushort* __restrict__ kbf, ushort* __restrict__ vbfT)
{
    __shared__ __align__(16) ushort S[14336];
    dev_qkv(blockIdx.x, S, xbf, wqbf, wkbf, wvbf, bq, bk, bv, qbf, kbf, vbfT);
}

__global__ __launch_bounds__(256, 3) void attn_k(
    const ushort* __restrict__ qbf, const ushort* __restrict__ kbf,
    const ushort* __restrict__ vbfT,
    const float* __restrict__ rph, const float* __restrict__ rpw,
    ushort* __restrict__ abf2)
{
    __shared__ __align__(16) ushort S[20480];
    dev_attn(blockIdx.x, S, qbf, kbf, vbfT, rph, rpw, abf2);
}

__global__ __launch_bounds__(256, 2) void proj_k(
    const ushort* __restrict__ abf2, const ushort* __restrict__ pwbf,
    const float* __restrict__ pb, float* __restrict__ out)
{
    __shared__ __align__(16) ushort S[20480];
    dev_proj(blockIdx.x, S, abf2, pwbf, pb, out);
}

extern "C" void kernel_launch(void* const* d_in, const int* in_sizes, int n_in,
                              void* d_out, int out_size, void* d_ws, size_t ws_size,
                              hipStream_t stream) {
    (void)in_sizes; (void)n_in; (void)out_size; (void)ws_size;
    const float* x   = (const float*)d_in[0];
    const float* Wq  = (const float*)d_in[1];
    const float* Wk  = (const float*)d_in[2];
    const float* Wv  = (const float*)d_in[3];
    const float* bq  = (const float*)d_in[4];
    const float* bk  = (const float*)d_in[5];
    const float* bv  = (const float*)d_in[6];
    const float* rph = (const float*)d_in[7];
    const float* rpw = (const float*)d_in[8];
    const float* pw  = (const float*)d_in[9];
    const float* pb  = (const float*)d_in[10];
    float* out = (float*)d_out;
    ushort* ws = (ushort*)d_ws;

    // deterministic host-side path choice (pure queries, no stream ops)
    int dev = 0;
    hipGetDevice(&dev);
    int coop = 0;
    hipDeviceGetAttribute(&coop, hipDeviceAttributeCooperativeLaunch, dev);
    int ncu = 0;
    hipDeviceGetAttribute(&ncu, hipDeviceAttributeMultiprocessorCount, dev);
    int occ = 0;
    hipOccupancyMaxActiveBlocksPerMultiprocessor(&occ, mega_k, 256, 0);

    hipError_t st = hipErrorUnknown;
    if (coop && ncu > 0 && occ > 0) {
        int grid = occ * ncu;
        if (grid > 768) grid = 768;
        if (grid >= 192) {
            void* args[] = {
                (void*)&x, (void*)&Wq, (void*)&Wk, (void*)&Wv,
                (void*)&bq, (void*)&bk, (void*)&bv,
                (void*)&rph, (void*)&rpw, (void*)&pw, (void*)&pb,
                (void*)&out, (void*)&ws
            };
            st = hipLaunchCooperativeKernel((const void*)mega_k, dim3(grid), dim3(256),
                                            args, 0, stream);
        }
    }
    if (st != hipSuccess) {
        // proven 4-kernel path
        ushort* xbf  = ws;
        ushort* wqbf = ws + 3145728;
        ushort* wkbf = wqbf + 589824;
        ushort* wvbf = wkbf + 589824;
        ushort* pwbf = wvbf + 589824;
        ushort* qbf  = pwbf + 589824;
        ushort* kbf  = qbf  + 3145728;
        ushort* vbfT = kbf  + 3145728;
        ushort* abf2 = vbfT + 3145728;

        hipLaunchKernelGGL(cvt_k, dim3(5376), dim3(256), 0, stream,
                           x, Wq, Wk, Wv, pw, ws);
        hipLaunchKernelGGL(qkv_k, dim3(768), dim3(256), 0, stream,
                           xbf, wqbf, wkbf, wvbf, bq, bk, bv, qbf, kbf, vbfT);
        hipLaunchKernelGGL(attn_k, dim3(768), dim3(256), 0, stream,
                           qbf, kbf, vbfT, rph, rpw, abf2);
        hipLaunchKernelGGL(proj_k, dim3(512), dim3(256), 0, stream,
                           abf2, pwbf, pb, out);
    }
}

// Round 19
// 79.369 us; speedup vs baseline: 3.8534x; 3.8534x over previous
//
#include <hip/hip_runtime.h>
#include <hip/hip_bf16.h>
#include <math.h>

typedef float4 f4;
typedef __attribute__((ext_vector_type(8))) short bf16x8;
typedef __attribute__((ext_vector_type(4))) float f32x4;
typedef __attribute__((ext_vector_type(16))) float f32x16;

#define CD   768
#define SEQ  1024
#define NHD  12
#define DH   64

__device__ __forceinline__ ushort f2bf(float x) {
    union { __hip_bfloat16 h; ushort u; } v;
    v.h = __float2bfloat16(x);
    return v.u;
}
__device__ __forceinline__ unsigned pk2bf(float a, float b) {
    union { __hip_bfloat162 h; unsigned u; } v;
    v.h = __float22bfloat162_rn(make_float2(a, b));
    return v.u;
}
__device__ __forceinline__ bf16x8 mk_bf16x8(unsigned a, unsigned b, unsigned c, unsigned d) {
    union { unsigned u[4]; bf16x8 v; } r;
    r.u[0] = a; r.u[1] = b; r.u[2] = c; r.u[3] = d;
    return r.v;
}
__device__ __forceinline__ void gload_lds16(const ushort* g, ushort* l) {
    __builtin_amdgcn_global_load_lds((const __attribute__((address_space(1))) void*)g,
                                     (__attribute__((address_space(3))) void*)l, 16, 0, 0);
}

// ---------------- fp32 -> bf16 conversion pre-pass ---------------------------
__global__ __launch_bounds__(256) void cvt_bf16_k(
    const float* __restrict__ x, const float* __restrict__ Wq,
    const float* __restrict__ Wk, const float* __restrict__ Wv,
    const float* __restrict__ pw, ushort* __restrict__ dst)
{
    const int idx = blockIdx.x * 256 + threadIdx.x;
    if (idx >= 1376256) return;
    const int e = idx << 2;
    if (e < 4915200) {
        const float* src; int off;
        if      (e < 3145728) { src = x;  off = e; }
        else if (e < 3735552) { src = Wq; off = e - 3145728; }
        else if (e < 4325376) { src = Wk; off = e - 3735552; }
        else                  { src = Wv; off = e - 4325376; }
        const f4 v = *(const f4*)(src + off);
        uint2 o;
        o.x = pk2bf(v.x, v.y);
        o.y = pk2bf(v.z, v.w);
        *(uint2*)(dst + e) = o;
    } else {
        const int off = e - 4915200;          // pw linear = n*768 + k
        const int n = off / CD, k = off - n * CD;
        const f4 v = *(const f4*)(pw + off);
        uint2 o;
        o.x = pk2bf(v.x, v.y);
        o.y = pk2bf(v.z, v.w);
        *(uint2*)(dst + 4915200 + ((size_t)(k >> 6) * CD + n) * 64 + (k & 63)) = o;
    }
}

// ---------------- QKV projection: 128x96 tile, dbuf, XCD-swizzled grid --------
__global__ __launch_bounds__(256, 2) void qkv_mfma(
    const ushort* __restrict__ xbf,
    const ushort* __restrict__ wq, const ushort* __restrict__ wk, const ushort* __restrict__ wv,
    const float* __restrict__ bq, const float* __restrict__ bk, const float* __restrict__ bv,
    ushort* __restrict__ qbf, ushort* __restrict__ kbf, ushort* __restrict__ vbfT)
{
    __shared__ __align__(16) ushort Sq[28672];

    const int t = threadIdx.x;
    const int w = t >> 6, l = t & 63;
    const int lr = l & 15, lg = l >> 4;
    // XCD swizzle: group each m-block's 24 n-tiles onto one XCD
    const int swz = (blockIdx.x & 7) * 96 + (blockIdx.x >> 3);
    const int n0 = (swz % 24) * 96;
    const int m0 = (swz / 24) << 7;
    const int sel  = n0 / CD;
    const int nloc = n0 % CD;
    const ushort* Wb  = (sel == 0) ? wq : ((sel == 1) ? wk : wv);
    const float* bias = (sel == 0) ? bq : ((sel == 1) ? bk : bv);

    const int srow = (w << 3) + (l >> 3);
    const int scol = (l & 7) << 3;
    const ushort* Agl = xbf + (size_t)(m0 + srow) * CD + scol;
    const ushort* Bgl = Wb + (size_t)(nloc + srow) * CD + scol;

    f32x4 acc[4][3];
    #pragma unroll
    for (int mi = 0; mi < 4; ++mi)
        #pragma unroll
        for (int ni = 0; ni < 3; ++ni) acc[mi][ni] = (f32x4){0.f, 0.f, 0.f, 0.f};

    const int mb = (w >> 1) << 6;
    const int nb = (w & 1) * 48;

    #pragma unroll
    for (int i = 0; i < 4; ++i)
        gload_lds16(Agl + (size_t)(i << 5) * CD, &Sq[(i << 11) + (w << 9)]);
    #pragma unroll
    for (int i = 0; i < 3; ++i)
        gload_lds16(Bgl + (size_t)(i << 5) * CD, &Sq[8192 + (i << 11) + (w << 9)]);
    __syncthreads();

    for (int kt = 0; kt < 12; ++kt) {
        const int cb = (kt & 1) * 14336;
        if (kt < 11) {
            const int nbuf = ((kt + 1) & 1) * 14336;
            const int kc = (kt + 1) << 6;
            #pragma unroll
            for (int i = 0; i < 4; ++i)
                gload_lds16(Agl + (size_t)(i << 5) * CD + kc, &Sq[nbuf + (i << 11) + (w << 9)]);
            #pragma unroll
            for (int i = 0; i < 3; ++i)
                gload_lds16(Bgl + (size_t)(i << 5) * CD + kc, &Sq[nbuf + 8192 + (i << 11) + (w << 9)]);
        }
        #pragma unroll
        for (int kk = 0; kk < 2; ++kk) {
            bf16x8 af[4], bf[3];
            #pragma unroll
            for (int mi = 0; mi < 4; ++mi)
                af[mi] = *(const bf16x8*)&Sq[cb + (mb + (mi << 4) + lr) * 64 + (kk << 5) + (lg << 3)];
            #pragma unroll
            for (int ni = 0; ni < 3; ++ni)
                bf[ni] = *(const bf16x8*)&Sq[cb + 8192 + (nb + (ni << 4) + lr) * 64 + (kk << 5) + (lg << 3)];
            #pragma unroll
            for (int mi = 0; mi < 4; ++mi)
                #pragma unroll
                for (int ni = 0; ni < 3; ++ni)
                    acc[mi][ni] = __builtin_amdgcn_mfma_f32_16x16x32_bf16(af[mi], bf[ni], acc[mi][ni], 0, 0, 0);
        }
        __syncthreads();
    }

    ushort* Ep = Sq + w * 3072;

    float bl[3];
    #pragma unroll
    for (int ni = 0; ni < 3; ++ni) bl[ni] = bias[nloc + nb + (ni << 4) + lr];

    if (sel < 2) {
        #pragma unroll
        for (int mi = 0; mi < 4; ++mi)
            #pragma unroll
            for (int ni = 0; ni < 3; ++ni)
                #pragma unroll
                for (int reg = 0; reg < 4; ++reg)
                    Ep[((mi << 4) + (lg << 2) + reg) * 48 + (ni << 4) + lr] =
                        f2bf(acc[mi][ni][reg] + bl[ni]);
    } else {
        // V: transpose + pi-permute: key = mi*16+lg*4+reg ->
        // slot = (mi>>1)*32 + lg*8 + (mi&1)*4 + reg
        #pragma unroll
        for (int mi = 0; mi < 4; ++mi)
            #pragma unroll
            for (int ni = 0; ni < 3; ++ni)
                #pragma unroll
                for (int reg = 0; reg < 4; ++reg)
                    Ep[((ni << 4) + lr) * 64 +
                       ((mi >> 1) << 5) + (lg << 3) + ((mi & 1) << 2) + reg] =
                        f2bf(acc[mi][ni][reg] + bl[ni]);
    }
    __syncthreads();

    const int bi  = m0 >> 10;
    const int si0 = (m0 & 1023) + mb;
    if (sel < 2) {
        ushort* dbf = (sel == 0) ? qbf : kbf;
        #pragma unroll
        for (int i = 0; i < 6; ++i) {
            const int c0   = i << 3;
            const int head = (nloc + nb + c0) >> 6;
            const int dd0  = (nloc + nb + c0) & 63;
            const int bn   = bi * NHD + head;
            *(bf16x8*)(dbf + (((size_t)bn << 10) + si0 + l) * 64 + dd0) =
                *(const bf16x8*)(Ep + l * 48 + c0);
        }
    } else {
        #pragma unroll
        for (int i = 0; i < 6; ++i) {
            const int idx = (i << 6) + l;
            const int r   = idx >> 3, ch = idx & 7;
            const int head = (nloc + nb + r) >> 6;
            const int d    = (nloc + nb + r) & 63;
            const int bn   = bi * NHD + head;
            *(bf16x8*)(vbfT + (((size_t)(bn * DH + d)) << 10) + si0 + (ch << 3)) =
                *(const bf16x8*)(Ep + r * 64 + (ch << 3));
        }
    }
}

// ---------------- MFMA flash attention + fused rel, XCD-swizzled grid ---------
__global__ __launch_bounds__(256, 3) void attn_mfma(
    const ushort* __restrict__ qbf, const ushort* __restrict__ kbf,
    const ushort* __restrict__ vbfT,
    const float* __restrict__ rph, const float* __restrict__ rpw,
    ushort* __restrict__ abf2)
{
    __shared__ __align__(16) ushort KV[2][8192];
    __shared__ __align__(16) float rhs_[2048];

    const int t  = threadIdx.x;
    const int l  = t & 63, w = t >> 6;
    const int lr = l & 15, lg = l >> 4;
    // XCD swizzle: each XCD owns 6 whole heads (96 consecutive tiles)
    const int swz = (blockIdx.x & 7) * 96 + (blockIdx.x >> 3);
    const int qt = swz & 15, bn = swz >> 4;
    const int q0 = qt << 6;

    // ======== rel prologue (R12-verified) ========
    {
        const int p   = w >> 1;
        const int sub = w & 1;
        const int h   = (qt << 1) + p;
        const int q5  = l & 31, g = l >> 5;

        const ushort* qp = qbf + (((size_t)bn << 10) + (h << 5) + q5) * 64 + (g << 3);
        bf16x8 qf[4];
        #pragma unroll
        for (int c = 0; c < 4; ++c) qf[c] = *(const bf16x8*)(qp + (c << 4));

        float* PwF = (float*)&KV[0][0] + p * 2112;

        if (sub == 0) {
            f32x16 acch;
            #pragma unroll
            for (int i = 0; i < 16; ++i) acch[i] = 0.f;
            {
                const float* rp = rph + (size_t)(h + 31 - q5) * 64 + (g << 3);
                #pragma unroll
                for (int c = 0; c < 4; ++c) {
                    const f4 v0 = *(const f4*)(rp + (c << 4));
                    const f4 v1 = *(const f4*)(rp + (c << 4) + 4);
                    union { unsigned u[4]; bf16x8 v; } u;
                    u.u[0] = pk2bf(v0.x, v0.y); u.u[1] = pk2bf(v0.z, v0.w);
                    u.u[2] = pk2bf(v1.x, v1.y); u.u[3] = pk2bf(v1.z, v1.w);
                    acch = __builtin_amdgcn_mfma_f32_32x32x16_bf16(u.v, qf[c], acch, 0, 0, 0);
                }
            }
            #pragma unroll
            for (int r = 0; r < 16; r += 2) {
                const int k2 = (r & 3) + ((r >> 2) << 3) + (g << 2);
                *(float2*)&rhs_[((k2 >> 1) << 7) + (((p << 5) + q5) << 1)] =
                    make_float2(acch[r], acch[r + 1]);
            }
            f32x16 accw;
            #pragma unroll
            for (int i = 0; i < 16; ++i) accw[i] = 0.f;
            {
                const float* rp = rpw + (size_t)q5 * 64 + (g << 3);
                #pragma unroll
                for (int c = 0; c < 4; ++c) {
                    const f4 v0 = *(const f4*)(rp + (c << 4));
                    const f4 v1 = *(const f4*)(rp + (c << 4) + 4);
                    union { unsigned u[4]; bf16x8 v; } u;
                    u.u[0] = pk2bf(v0.x, v0.y); u.u[1] = pk2bf(v0.z, v0.w);
                    u.u[2] = pk2bf(v1.x, v1.y); u.u[3] = pk2bf(v1.z, v1.w);
                    accw = __builtin_amdgcn_mfma_f32_32x32x16_bf16(u.v, qf[c], accw, 0, 0, 0);
                }
            }
            #pragma unroll
            for (int r = 0; r < 16; ++r) {
                const int row = (r & 3) + ((r >> 2) << 3) + (g << 2);
                PwF[row * 33 + q5] = accw[r];
            }
        } else {
            f32x16 accw;
            #pragma unroll
            for (int i = 0; i < 16; ++i) accw[i] = 0.f;
            {
                const bool ok = (32 + q5) < 63;
                const float* rp = rpw + (size_t)(32 + q5) * 64 + (g << 3);
                #pragma unroll
                for (int c = 0; c < 4; ++c) {
                    union { unsigned u[4]; bf16x8 v; } u;
                    if (ok) {
                        const f4 v0 = *(const f4*)(rp + (c << 4));
                        const f4 v1 = *(const f4*)(rp + (c << 4) + 4);
                        u.u[0] = pk2bf(v0.x, v0.y); u.u[1] = pk2bf(v0.z, v0.w);
                        u.u[2] = pk2bf(v1.x, v1.y); u.u[3] = pk2bf(v1.z, v1.w);
                    } else {
                        u.u[0] = 0u; u.u[1] = 0u; u.u[2] = 0u; u.u[3] = 0u;
                    }
                    accw = __builtin_amdgcn_mfma_f32_32x32x16_bf16(u.v, qf[c], accw, 0, 0, 0);
                }
            }
            #pragma unroll
            for (int r = 0; r < 16; ++r) {
                const int row = (r & 3) + ((r >> 2) << 3) + (g << 2) + 32;
                PwF[row * 33 + q5] = accw[r];
            }
        }
    }
    __syncthreads();

    float rw8[8];
    {
        const int p   = w >> 1;
        const int q5w = ((w & 1) << 4) + lr;
        const float* PwF = (float*)&KV[0][0] + p * 2112;
        #pragma unroll
        for (int b = 0; b < 2; ++b)
            #pragma unroll
            for (int reg = 0; reg < 4; ++reg) {
                const int k2 = (b << 4) + (lg << 2) + reg;
                rw8[(b << 2) + reg] = PwF[(q5w + 31 - k2) * 33 + q5w];
            }
    }
    __syncthreads();

    // ======== main loop (R15-verified) ========
    const ushort* qp = qbf + (((size_t)bn << 10) + q0 + w * 16 + lr) * DH + lg * 8;
    const bf16x8 qa0 = *(const bf16x8*)qp;
    const bf16x8 qa1 = *(const bf16x8*)(qp + 32);

    const int rhbase = (w * 16 + lr) << 1;

    const int i0   = w << 1;
    const int rsub = l >> 3;
    const int coff = ((l & 7) ^ rsub) << 3;
    const size_t kbase = ((size_t)bn << 16);
    const ushort* kp0 = kbf + kbase + (size_t)((i0 << 3) + rsub) * 64 + coff;
    const ushort* kp1 = kp0 + 512;
    const ushort* vp0 = vbfT + kbase + ((size_t)((i0 << 3) + rsub) << 10) + coff;
    const ushort* vp1 = vp0 + 8192;
    const int lds0 = i0 << 9;

    f32x4 oc[4];
    #pragma unroll
    for (int nf = 0; nf < 4; ++nf) oc[nf] = (f32x4){0.f, 0.f, 0.f, 0.f};
    f32x4 sumc = (f32x4){0.f, 0.f, 0.f, 0.f};
    bf16x8 ones;
    #pragma unroll
    for (int i = 0; i < 8; ++i) ones[i] = (short)0x3F80;

    const int s0c = lg ^ (lr & 7);

    gload_lds16(kp0, &KV[0][lds0]);
    gload_lds16(kp1, &KV[0][lds0 + 512]);
    gload_lds16(vp0, &KV[0][4096 + lds0]);
    gload_lds16(vp1, &KV[0][4096 + lds0 + 512]);
    __syncthreads();

    for (int kt = 0; kt < 16; ++kt) {
        const int cur = kt & 1;
        if (kt < 15) {
            ushort* nb_ = &KV[cur ^ 1][0];
            gload_lds16(kp0 + ((kt + 1) << 12), nb_ + lds0);
            gload_lds16(kp1 + ((kt + 1) << 12), nb_ + lds0 + 512);
            gload_lds16(vp0 + ((kt + 1) << 6), nb_ + 4096 + lds0);
            gload_lds16(vp1 + ((kt + 1) << 6), nb_ + 4096 + lds0 + 512);
        }
        const ushort* Kl = &KV[cur][0];
        const ushort* Vt = &KV[cur][4096];
        const float2 rh = *(const float2*)&rhs_[(kt << 7) + rhbase];

        f32x4 sc[4];
        #pragma unroll
        for (int f = 0; f < 4; ++f) {
            f32x4 c = (f32x4){0.f, 0.f, 0.f, 0.f};
            const int rb = (f * 16 + lr) * 64;
            const bf16x8 kb0 = *(const bf16x8*)&Kl[rb + (s0c << 3)];
            const bf16x8 kb1 = *(const bf16x8*)&Kl[rb + ((s0c ^ 4) << 3)];
            c = __builtin_amdgcn_mfma_f32_16x16x32_bf16(kb0, qa0, c, 0, 0, 0);
            c = __builtin_amdgcn_mfma_f32_16x16x32_bf16(kb1, qa1, c, 0, 0, 0);
            sc[f] = c;
        }

        unsigned ua[4], ub[4];
        #pragma unroll
        for (int f = 0; f < 4; ++f) {
            const float rhv = (f & 2) ? rh.y : rh.x;
            const int rb8 = (f & 1) << 2;
            const float e0 = __expf(fmaf(sc[f][0], 0.125f, rhv + rw8[rb8 + 0]));
            const float e1 = __expf(fmaf(sc[f][1], 0.125f, rhv + rw8[rb8 + 1]));
            const float e2 = __expf(fmaf(sc[f][2], 0.125f, rhv + rw8[rb8 + 2]));
            const float e3 = __expf(fmaf(sc[f][3], 0.125f, rhv + rw8[rb8 + 3]));
            unsigned* du = (f & 2) ? ub : ua;
            du[((f & 1) << 1) + 0] = pk2bf(e0, e1);
            du[((f & 1) << 1) + 1] = pk2bf(e2, e3);
        }
        const bf16x8 pa0 = mk_bf16x8(ua[0], ua[1], ua[2], ua[3]);
        const bf16x8 pa1 = mk_bf16x8(ub[0], ub[1], ub[2], ub[3]);

        sumc = __builtin_amdgcn_mfma_f32_16x16x32_bf16(pa0, ones, sumc, 0, 0, 0);
        sumc = __builtin_amdgcn_mfma_f32_16x16x32_bf16(pa1, ones, sumc, 0, 0, 0);
        #pragma unroll
        for (int nf = 0; nf < 4; ++nf) {
            const int rb = (nf * 16 + lr) * 64;
            const bf16x8 vb0 = *(const bf16x8*)&Vt[rb + (s0c << 3)];
            const bf16x8 vb1 = *(const bf16x8*)&Vt[rb + ((s0c ^ 4) << 3)];
            oc[nf] = __builtin_amdgcn_mfma_f32_16x16x32_bf16(pa0, vb0, oc[nf], 0, 0, 0);
            oc[nf] = __builtin_amdgcn_mfma_f32_16x16x32_bf16(pa1, vb1, oc[nf], 0, 0, 0);
        }
        __syncthreads();
    }

    const int bi = bn / NHD, hn = bn - bi * NHD;
    #pragma unroll
    for (int reg = 0; reg < 4; ++reg) {
        const float inv = 1.f / sumc[reg];
        const int row = q0 + w * 16 + lg * 4 + reg;
        ushort* dst = abf2 + ((size_t)hn * 4096 + (bi << 10) + row) * 64 + lr;
        union { unsigned u; ushort2 s2; } a, b;
        a.u = pk2bf(oc[0][reg] * inv, oc[1][reg] * inv);
        b.u = pk2bf(oc[2][reg] * inv, oc[3][reg] * inv);
        dst[0]  = a.s2.x;
        dst[16] = a.s2.y;
        dst[32] = b.s2.x;
        dst[48] = b.s2.y;
    }
}

// ---------------- output projection: 64x96 tile, dbuf, XCD-swizzled grid ------
__global__ __launch_bounds__(256, 2) void proj_mfma(
    const ushort* __restrict__ abf2, const ushort* __restrict__ pwbf2,
    const float* __restrict__ pb, float* __restrict__ out)
{
    __shared__ __align__(16) ushort Sp[20480];

    const int t = threadIdx.x;
    const int w = t >> 6, l = t & 63;
    const int lr = l & 15, lg = l >> 4;
    const int swz = (blockIdx.x & 7) * 64 + (blockIdx.x >> 3);
    const int n0 = (swz & 7) * 96;
    const int m0 = (swz >> 3) << 6;

    const int srow = l >> 3;
    const int scol = (l & 7) << 3;
    const ushort* Agl = abf2 + (size_t)(m0 + (w << 4) + srow) * 64 + scol;
    const ushort* Bgl = pwbf2 + (size_t)(n0 + w * 24 + srow) * 64 + scol;

    f32x4 acc[2][3];
    #pragma unroll
    for (int mi = 0; mi < 2; ++mi)
        #pragma unroll
        for (int ni = 0; ni < 3; ++ni) acc[mi][ni] = (f32x4){0.f, 0.f, 0.f, 0.f};

    const int mb = (w >> 1) << 5;
    const int nb = (w & 1) * 48;

    #pragma unroll
    for (int i = 0; i < 2; ++i)
        gload_lds16(Agl + (i << 9), &Sp[(w << 10) + (i << 9)]);
    #pragma unroll
    for (int j = 0; j < 3; ++j)
        gload_lds16(Bgl + (j << 9), &Sp[4096 + w * 1536 + (j << 9)]);
    __syncthreads();

    for (int kt = 0; kt < 12; ++kt) {
        const int cb = (kt & 1) * 10240;
        if (kt < 11) {
            const int nbuf = ((kt + 1) & 1) * 10240;
            const size_t pA = (size_t)(kt + 1) * 262144;
            const size_t pB = (size_t)(kt + 1) * 49152;
            #pragma unroll
            for (int i = 0; i < 2; ++i)
                gload_lds16(Agl + pA + (i << 9), &Sp[nbuf + (w << 10) + (i << 9)]);
            #pragma unroll
            for (int j = 0; j < 3; ++j)
                gload_lds16(Bgl + pB + (j << 9), &Sp[nbuf + 4096 + w * 1536 + (j << 9)]);
        }
        #pragma unroll
        for (int kk = 0; kk < 2; ++kk) {
            bf16x8 af[2], bf[3];
            #pragma unroll
            for (int mi = 0; mi < 2; ++mi)
                af[mi] = *(const bf16x8*)&Sp[cb + (mb + (mi << 4) + lr) * 64 + (kk << 5) + (lg << 3)];
            #pragma unroll
            for (int ni = 0; ni < 3; ++ni)
                bf[ni] = *(const bf16x8*)&Sp[cb + 4096 + (nb + (ni << 4) + lr) * 64 + (kk << 5) + (lg << 3)];
            #pragma unroll
            for (int mi = 0; mi < 2; ++mi)
                #pragma unroll
                for (int ni = 0; ni < 3; ++ni)
                    acc[mi][ni] = __builtin_amdgcn_mfma_f32_16x16x32_bf16(af[mi], bf[ni], acc[mi][ni], 0, 0, 0);
        }
        __syncthreads();
    }

    float bl[3];
    #pragma unroll
    for (int ni = 0; ni < 3; ++ni) bl[ni] = pb[n0 + nb + (ni << 4) + lr];
    #pragma unroll
    for (int mi = 0; mi < 2; ++mi)
        #pragma unroll
        for (int ni = 0; ni < 3; ++ni)
            #pragma unroll
            for (int reg = 0; reg < 4; ++reg)
                out[(size_t)(m0 + mb + (mi << 4) + (lg << 2) + reg) * CD
                    + n0 + nb + (ni << 4) + lr] = acc[mi][ni][reg] + bl[ni];
}

extern "C" void kernel_launch(void* const* d_in, const int* in_sizes, int n_in,
                              void* d_out, int out_size, void* d_ws, size_t ws_size,
                              hipStream_t stream) {
    (void)in_sizes; (void)n_in; (void)out_size; (void)ws_size;
    const float* x   = (const float*)d_in[0];
    const float* Wq  = (const float*)d_in[1];
    const float* Wk  = (const float*)d_in[2];
    const float* Wv  = (const float*)d_in[3];
    const float* bq  = (const float*)d_in[4];
    const float* bk  = (const float*)d_in[5];
    const float* bv  = (const float*)d_in[6];
    const float* rph = (const float*)d_in[7];
    const float* rpw = (const float*)d_in[8];
    const float* pw  = (const float*)d_in[9];
    const float* pb  = (const float*)d_in[10];
    float* out = (float*)d_out;

    ushort* cvt  = (ushort*)d_ws;
    ushort* xbf  = cvt;
    ushort* wqbf = cvt + 3145728;
    ushort* wkbf = wqbf + 589824;
    ushort* wvbf = wkbf + 589824;
    ushort* pwbf = wvbf + 589824;      // panel layout [k/64][768][64]
    ushort* qbf  = pwbf + 589824;
    ushort* kbf  = qbf  + 3145728;
    ushort* vbfT = kbf  + 3145728;
    ushort* abf2 = vbfT + 3145728;     // [head][4096][64]

    hipLaunchKernelGGL(cvt_bf16_k, dim3(5376), dim3(256), 0, stream,
                       x, Wq, Wk, Wv, pw, cvt);
    hipLaunchKernelGGL(qkv_mfma, dim3(768), dim3(256), 0, stream,
                       xbf, wqbf, wkbf, wvbf, bq, bk, bv, qbf, kbf, vbfT);
    hipLaunchKernelGGL(attn_mfma, dim3(768), dim3(256), 0, stream,
                       qbf, kbf, vbfT, rph, rpw, abf2);
    hipLaunchKernelGGL(proj_mfma, dim3(512), dim3(256), 0, stream,
                       abf2, pwbf, pb, out);
}